// Round 11
// baseline (155.139 us; speedup 1.0000x reference)
//
#include <hip/hip_runtime.h>
#include <hip/hip_fp16.h>
#include <cmath>
#include <type_traits>

#define NEG_SLOPE 0.2f
#define BSHIFT 6          // 64 nodes per bucket
#define NBKMAX 1024       // supports N <= 65536
#define BCAP   2048       // per-bucket slab capacity (mean 1024, max ~1200)

typedef _Float16 f16x8 __attribute__((ext_vector_type(8)));
typedef float    f32x4 __attribute__((ext_vector_type(4)));

// XOR-swizzled LDS byte address for [row][kbyte] fp16 tiles (256B rows).
__device__ __forceinline__ int swz(int row, int kbyte) {
    return (row << 8) + (kbyte ^ ((row & 7) << 4));
}

// ---- one-time: Wt[n][k] fp16 = W[k][n] transposed; block 0 zeroes grel ----
__global__ __launch_bounds__(256) void transp(const float* __restrict__ W1,
                                              const float* __restrict__ W2,
                                              __half* __restrict__ Wt1,
                                              __half* __restrict__ Wt2,
                                              int* __restrict__ grel)
{
    int b = blockIdx.x;            // 0..7
    int t = threadIdx.x;
    if (b == 0) {
#pragma unroll
        for (int i = 0; i < 4; ++i) grel[t + 256 * i] = 0;
    }
    const float* W = (b < 4) ? W1 : W2;
    __half* Wt = (b < 4) ? Wt1 : Wt2;
    int q = b & 3;
#pragma unroll
    for (int i = 0; i < 4; ++i) {
        int idx = q * 1024 + t + 256 * i;   // float4 index 0..4095
        int k = idx >> 5, nq = idx & 31;
        float4 v = ((const float4*)W)[idx];
        const float* vp = (const float*)&v;
#pragma unroll
        for (int j = 0; j < 4; ++j)
            Wt[(size_t)(nq * 4 + j) * 128 + k] = __float2half(vp[j]);
    }
}

// ------- MFMA GEMM + fused attention coefficients (device body) -------
template<typename AT>
__device__ __forceinline__ void gemm_body(char* lds,
                                          const AT* __restrict__ A,
                                          const __half* __restrict__ Wt,
                                          const float* __restrict__ al,
                                          const float* __restrict__ ar,
                                          __half* __restrict__ feat_h,
                                          float* __restrict__ el,
                                          float* __restrict__ er,
                                          int nrows, int bid)
{
    int t = threadIdx.x;
    int r0 = bid * 64;

    // ---- stage A (64 rows x 128 k, fp16, swizzled) ----
#pragma unroll
    for (int i = 0; i < 4; ++i) {
        int cid = t + 256 * i;            // 0..1023 : 16B chunks
        int row = cid >> 4, kc = cid & 15;
        int gr = r0 + row;
        f16x8 hv;
        if constexpr (std::is_same<AT, float>::value) {
            float4 v0 = make_float4(0, 0, 0, 0), v1 = v0;
            if (gr < nrows) {
                v0 = ((const float4*)A)[(size_t)gr * 32 + kc * 2];
                v1 = ((const float4*)A)[(size_t)gr * 32 + kc * 2 + 1];
            }
            hv[0] = (_Float16)v0.x; hv[1] = (_Float16)v0.y;
            hv[2] = (_Float16)v0.z; hv[3] = (_Float16)v0.w;
            hv[4] = (_Float16)v1.x; hv[5] = (_Float16)v1.y;
            hv[6] = (_Float16)v1.z; hv[7] = (_Float16)v1.w;
        } else {
            uint4 u = make_uint4(0, 0, 0, 0);
            if (gr < nrows) u = ((const uint4*)A)[(size_t)gr * 16 + kc];
            hv = *(const f16x8*)&u;
        }
        *(f16x8*)(lds + swz(row, kc * 16)) = hv;
    }
    // ---- stage B = Wt (128 n x 128 k, fp16, swizzled) ----
#pragma unroll
    for (int i = 0; i < 8; ++i) {
        int cid = t + 256 * i;            // 0..2047
        int n = cid >> 4, kc = cid & 15;
        uint4 u = ((const uint4*)Wt)[(size_t)n * 16 + kc];
        *(uint4*)(lds + 16384 + swz(n, kc * 16)) = u;
    }
    __syncthreads();

    int w = t >> 6, lane = t & 63;
    int l15 = lane & 15, g = lane >> 4;

    f32x4 acc[8];
#pragma unroll
    for (int ct = 0; ct < 8; ++ct) acc[ct] = (f32x4){0.f, 0.f, 0.f, 0.f};

#pragma unroll
    for (int ks = 0; ks < 4; ++ks) {
        f16x8 a = *(const f16x8*)(lds + swz(w * 16 + l15, ks * 64 + g * 16));
#pragma unroll
        for (int ct = 0; ct < 8; ++ct) {
            f16x8 b = *(const f16x8*)(lds + 16384 + swz(ct * 16 + l15, ks * 64 + g * 16));
            acc[ct] = __builtin_amdgcn_mfma_f32_16x16x32_f16(a, b, acc[ct], 0, 0, 0);
        }
    }

    // ---- feat fp16 store: lane holds C[m][n], m=w*16+g*4+j, n=ct*16+l15 ----
#pragma unroll
    for (int j = 0; j < 4; ++j) {
        int gr = r0 + w * 16 + g * 4 + j;
        if (gr < nrows) {
#pragma unroll
            for (int ct = 0; ct < 8; ++ct)
                feat_h[(size_t)gr * 128 + ct * 16 + l15] = __float2half(acc[ct][j]);
        }
    }

    // ---- fused el/er ----
    float alf[8], arf[8];
#pragma unroll
    for (int z = 0; z < 8; ++z) { alf[z] = al[z * 16 + l15]; arf[z] = ar[z * 16 + l15]; }
    float elv[4][4], erv[4][4];
#pragma unroll
    for (int j = 0; j < 4; ++j)
#pragma unroll
        for (int h = 0; h < 4; ++h) {
            elv[j][h] = acc[2*h][j] * alf[2*h] + acc[2*h+1][j] * alf[2*h+1];
            erv[j][h] = acc[2*h][j] * arf[2*h] + acc[2*h+1][j] * arf[2*h+1];
        }
#pragma unroll
    for (int off = 1; off < 16; off <<= 1) {
#pragma unroll
        for (int j = 0; j < 4; ++j)
#pragma unroll
            for (int h = 0; h < 4; ++h) {
                elv[j][h] += __shfl_xor(elv[j][h], off);
                erv[j][h] += __shfl_xor(erv[j][h], off);
            }
    }
    if (l15 == 0) {
#pragma unroll
        for (int j = 0; j < 4; ++j) {
            int gr = r0 + w * 16 + g * 4 + j;
            if (gr < nrows) {
#pragma unroll
                for (int h = 0; h < 4; ++h) {
                    el[gr * 4 + h] = elv[j][h];
                    er[gr * 4 + h] = erv[j][h];
                }
            }
        }
    }
}

// ---- part A body: partition (dst,src) pairs into per-bucket slabs ----
__device__ __forceinline__ void part_a_body(char* smem,
                                            const int* __restrict__ src,
                                            const int* __restrict__ dst,
                                            int* __restrict__ grel,
                                            unsigned long long* __restrict__ ebuf,
                                            int ne, int nchunk, int bid)
{
    int* cnt   = (int*)smem;            // [1024]
    int* rbase = cnt + NBKMAX;          // [1024] relative slab start
    int t = threadIdx.x;
    int c0 = bid * nchunk;
    int c1 = c0 + nchunk; if (c1 > ne) c1 = ne;
    for (int b = t; b < NBKMAX; b += 256) cnt[b] = 0;
    __syncthreads();
    for (int i = c0 + t; i < c1; i += 256)
        atomicAdd(&cnt[dst[i] >> BSHIFT], 1);
    __syncthreads();
    for (int b = t; b < NBKMAX; b += 256) {
        int c = cnt[b];
        rbase[b] = c ? atomicAdd(&grel[b], c) : 0;
        cnt[b] = 0;
    }
    __syncthreads();
    for (int i = c0 + t; i < c1; i += 256) {
        int d = dst[i];
        int b = d >> BSHIFT;
        int p = atomicAdd(&cnt[b], 1);
        int slot = rbase[b] + p;
        if (slot < BCAP)
            ebuf[(size_t)b * BCAP + slot] =
                ((unsigned long long)(unsigned)d << 32) | (unsigned)src[i];
    }
}

// ---- merged dispatch: gemm layer-1 blocks + part_a blocks (independent) ----
__global__ __launch_bounds__(256) void gemm1_parta(const float* __restrict__ X,
                                                   const __half* __restrict__ Wt1,
                                                   const float* __restrict__ al,
                                                   const float* __restrict__ ar,
                                                   __half* __restrict__ feat_h,
                                                   float* __restrict__ el,
                                                   float* __restrict__ er, int nrows,
                                                   const int* __restrict__ src,
                                                   const int* __restrict__ dst,
                                                   int* __restrict__ grel,
                                                   unsigned long long* __restrict__ ebuf,
                                                   int ne, int nchunk, int ngemm)
{
    __shared__ __align__(16) char smem[49152];
    int bid = blockIdx.x;
    if (bid < ngemm)
        gemm_body<float>(smem, X, Wt1, al, ar, feat_h, el, er, nrows, bid);
    else
        part_a_body(smem, src, dst, grel, ebuf, ne, nchunk, bid - ngemm);
}

// ---- standalone gemm (layer 2) ----
__global__ __launch_bounds__(256) void gemm_mfma_h(const __half* __restrict__ A,
                                                   const __half* __restrict__ Wt,
                                                   const float* __restrict__ al,
                                                   const float* __restrict__ ar,
                                                   __half* __restrict__ feat_h,
                                                   float* __restrict__ el,
                                                   float* __restrict__ er, int nrows)
{
    __shared__ __align__(16) char smem[49152];
    gemm_body<__half>(smem, A, Wt, al, ar, feat_h, el, er, nrows, blockIdx.x);
}

// ------- bucketed softmax + aggregation: one block per 64-node bucket -------
// Phase 1 (in-LDS CSR): histogram + scan + scatter of the bucket's slab.
// Phase 2: 4 waves x 16 nodes each, per-node softmax-weighted gather.
// LAYER 1: hbuf_h[n,128] (fp16) = elu(sum_e a*feat[src] + b)
// LAYER 2: out[n,32] (fp32)     = mean_h(sum_e a*feat[src] + b)
template<int LAYER>
__global__ __launch_bounds__(256) void agg_bucket(const __half2* __restrict__ feat,
                                                  const float* __restrict__ el,
                                                  const float* __restrict__ er,
                                                  const int* __restrict__ grel,
                                                  const unsigned long long* __restrict__ ebuf,
                                                  const float* __restrict__ bias,
                                                  void* __restrict__ out, int nnodes)
{
    __shared__ int   hcnt[64];
    __shared__ int   curs[64];
    __shared__ int   loffs[65];
    __shared__ int   lsrc[BCAP];
    __shared__ float w_sh[4][256];

    int b = blockIdx.x;
    int t = threadIdx.x;
    int lane = t & 63;
    int wid  = t >> 6;
    int node0 = b << BSHIFT;
    int count = grel[b]; if (count > BCAP) count = BCAP;
    const unsigned long long* eb = ebuf + (size_t)b * BCAP;

    // --- in-LDS CSR build ---
    if (t < 64) hcnt[t] = 0;
    __syncthreads();
    for (int i = t; i < count; i += 256) {
        int d = (int)(eb[i] >> 32);
        atomicAdd(&hcnt[d - node0], 1);
    }
    __syncthreads();
    if (wid == 0) {
        int v = hcnt[lane];
        int x = v;
#pragma unroll
        for (int off = 1; off < 64; off <<= 1) {
            int y = __shfl_up(x, off);
            if (lane >= off) x += y;
        }
        loffs[lane + 1] = x;
        if (lane == 0) loffs[0] = 0;
        curs[lane] = x - v;
    }
    __syncthreads();
    for (int i = t; i < count; i += 256) {
        unsigned long long e = eb[i];
        int d = (int)(e >> 32);
        int p = atomicAdd(&curs[d - node0], 1);
        lsrc[p] = (int)(unsigned)(e & 0xffffffffu);
    }
    __syncthreads();

    // --- per-node aggregation: wave wid owns nodes [wid*16, wid*16+16) ---
    const float4* el4 = (const float4*)el;
    int h = lane >> 4;
    int c = lane * 2;

    for (int ln = wid * 16; ln < wid * 16 + 16; ++ln) {
        int node = node0 + ln;
        if (node >= nnodes) break;
        int beg = loffs[ln], end = loffs[ln + 1];
        float4 er4 = ((const float4*)er)[node];

        float accx = 0.f, accy = 0.f;
        float d0 = 0.f, d1 = 0.f, d2 = 0.f, d3 = 0.f;

        for (int cbeg = beg; cbeg < end; cbeg += 64) {
            int cnt = end - cbeg; if (cnt > 64) cnt = 64;
            int myS = (lane < cnt) ? lsrc[cbeg + lane] : 0;
            float4 e4 = el4[myS];
            float ex0 = 0.f, ex1 = 0.f, ex2 = 0.f, ex3 = 0.f;
            if (lane < cnt) {
                float e;
                e = e4.x + er4.x; ex0 = __expf(fmaxf(e, 0.f) + NEG_SLOPE * fminf(e, 0.f));
                e = e4.y + er4.y; ex1 = __expf(fmaxf(e, 0.f) + NEG_SLOPE * fminf(e, 0.f));
                e = e4.z + er4.z; ex2 = __expf(fmaxf(e, 0.f) + NEG_SLOPE * fminf(e, 0.f));
                e = e4.w + er4.w; ex3 = __expf(fmaxf(e, 0.f) + NEG_SLOPE * fminf(e, 0.f));
                d0 += ex0; d1 += ex1; d2 += ex2; d3 += ex3;
            }
            ((float4*)&w_sh[wid][0])[lane] = make_float4(ex0, ex1, ex2, ex3);
            // wave-private LDS: producer == consumer wave, in-order DS pipe

#pragma unroll
            for (int g = 0; g < 4; ++g) {
                if (g * 16 < cnt) {
                    __half2 f[16]; float w[16];
#pragma unroll
                    for (int k = 0; k < 16; ++k) {
                        int s = __builtin_amdgcn_readlane(myS, g * 16 + k);
                        f[k] = feat[(size_t)s * 64 + lane];
                        w[k] = w_sh[wid][(g * 16 + k) * 4 + h];
                    }
#pragma unroll
                    for (int k = 0; k < 16; ++k) {
                        float2 ff = __half22float2(f[k]);
                        accx += ff.x * w[k];
                        accy += ff.y * w[k];
                    }
                }
            }
        }

#pragma unroll
        for (int off = 32; off; off >>= 1) {
            d0 += __shfl_xor(d0, off);
            d1 += __shfl_xor(d1, off);
            d2 += __shfl_xor(d2, off);
            d3 += __shfl_xor(d3, off);
        }
        float dh   = h == 0 ? d0 : h == 1 ? d1 : h == 2 ? d2 : d3;
        float invh = dh > 0.f ? 1.f / dh : 0.f;
        accx *= invh; accy *= invh;

        if (LAYER == 1) {
            float v0 = accx + bias[c];
            float v1 = accy + bias[c + 1];
            v0 = v0 > 0.f ? v0 : expm1f(v0);
            v1 = v1 > 0.f ? v1 : expm1f(v1);
            ((__half2*)out)[(size_t)node * 64 + lane] = __floats2half2_rn(v0, v1);
        } else {
            float v0 = accx + bias[c];
            float v1 = accy + bias[c + 1];
            v0 += __shfl_xor(v0, 16); v0 += __shfl_xor(v0, 32);
            v1 += __shfl_xor(v1, 16); v1 += __shfl_xor(v1, 32);
            if (lane < 16)
                ((float2*)out)[(size_t)node * 16 + lane] = make_float2(v0 * 0.25f, v1 * 0.25f);
        }
    }
}

template __global__ void agg_bucket<1>(const __half2*, const float*, const float*,
                                       const int*, const unsigned long long*,
                                       const float*, void*, int);
template __global__ void agg_bucket<2>(const __half2*, const float*, const float*,
                                       const int*, const unsigned long long*,
                                       const float*, void*, int);

// ---------------- launcher ----------------
extern "C" void kernel_launch(void* const* d_in, const int* in_sizes, int n_in,
                              void* d_out, int out_size, void* d_ws, size_t ws_size,
                              hipStream_t stream)
{
    const float* X   = (const float*)d_in[0];
    const int*   src = (const int*)d_in[1];
    const int*   dst = (const int*)d_in[2];
    const float* W1  = (const float*)d_in[3];
    const float* al1 = (const float*)d_in[4];
    const float* ar1 = (const float*)d_in[5];
    const float* b1  = (const float*)d_in[6];
    const float* W2  = (const float*)d_in[7];
    const float* al2 = (const float*)d_in[8];
    const float* ar2 = (const float*)d_in[9];
    const float* b2  = (const float*)d_in[10];
    float* out = (float*)d_out;

    const int N = in_sizes[0] / 128;
    const int E = in_sizes[1];
    const int NBK = (N + 63) >> BSHIFT;        // 64-node buckets
    const int NCH = (E + 255) / 256;           // part_a chunk per block (256 blocks)
    const int NGEMM = (N + 63) / 64;

    size_t off = 0;
    char* base = (char*)d_ws;
    auto alloc = [&](size_t bytes) -> void* {
        void* p = base + off;
        off += (bytes + 255) & ~(size_t)255;
        return p;
    };
    __half* feat_h = (__half*)alloc((size_t)N * 128 * 2);
    __half* hbuf_h = (__half*)alloc((size_t)N * 128 * 2);
    float*  el     = (float*)alloc((size_t)N * 4 * 4);
    float*  er     = (float*)alloc((size_t)N * 4 * 4);
    unsigned long long* ebuf = (unsigned long long*)alloc((size_t)NBKMAX * BCAP * 8);
    int*    grel   = (int*)alloc(NBKMAX * 4);
    __half* Wt1    = (__half*)alloc(128 * 128 * 2);
    __half* Wt2    = (__half*)alloc(128 * 128 * 2);
    (void)ws_size; (void)n_in; (void)out_size;

    // d1: weight transposes + grel zeroing
    transp<<<8, 256, 0, stream>>>(W1, W2, Wt1, Wt2, grel);

    // d2: layer-1 MFMA GEMM (+el/er)  ∥  edge partition into bucket slabs
    gemm1_parta<<<NGEMM + 256, 256, 0, stream>>>(X, Wt1, al1, ar1, feat_h, el, er, N,
                                                 src, dst, grel, ebuf, E, NCH, NGEMM);

    // d3: layer-1 bucketed aggregation (in-LDS CSR) -> elu(acc + b1) fp16
    agg_bucket<1><<<NBK, 256, 0, stream>>>((const __half2*)feat_h, el, er, grel, ebuf, b1, hbuf_h, N);

    // d4: layer-2 GEMM
    gemm_mfma_h<<<NGEMM, 256, 0, stream>>>(hbuf_h, Wt2, al2, ar2, feat_h, el, er, N);

    // d5: layer-2 bucketed aggregation -> out
    agg_bucket<2><<<NBK, 256, 0, stream>>>((const __half2*)feat_h, el, er, grel, ebuf, b2, out, N);
}

// Round 12
// 130.116 us; speedup vs baseline: 1.1923x; 1.1923x over previous
//
#include <hip/hip_runtime.h>
#include <hip/hip_fp16.h>
#include <cmath>
#include <type_traits>

#define NEG_SLOPE 0.2f
#define BSHIFT 7          // 128 nodes per bucket
#define NBKMAX 512        // supports N <= 65536
#define BCAP   4096       // per-bucket slab capacity in ebuf (Poisson(2048) max ~2300)

typedef _Float16 f16x8 __attribute__((ext_vector_type(8)));
typedef float    f32x4 __attribute__((ext_vector_type(4)));

// XOR-swizzled LDS byte address for [row][kbyte] fp16 tiles (256B rows).
__device__ __forceinline__ int swz(int row, int kbyte) {
    return (row << 8) + (kbyte ^ ((row & 7) << 4));
}

// 512-entry exclusive scan in LDS (256 threads); sc gets exclusive prefix.
__device__ __forceinline__ void scan512_excl(const int* __restrict__ g,
                                             int* sc, int* ws, int t) {
    int lane = t & 63, w = t >> 6;
    int a = g[2 * t], b = g[2 * t + 1];
    int ps = a + b;
    int x = ps;
#pragma unroll
    for (int off = 1; off < 64; off <<= 1) {
        int y = __shfl_up(x, off);
        if (lane >= off) x += y;
    }
    if (lane == 63) ws[w] = x;
    __syncthreads();
    int pre = 0;
#pragma unroll
    for (int i = 0; i < 4; ++i) pre += (i < w) ? ws[i] : 0;
    int e0 = pre + x - ps;
    sc[2 * t] = e0;
    sc[2 * t + 1] = e0 + a;
    __syncthreads();
}

// ---- one-time: Wt[n][k] fp16 = W[k][n] transposed; block 0 zeroes grel ----
__global__ __launch_bounds__(256) void transp(const float* __restrict__ W1,
                                              const float* __restrict__ W2,
                                              __half* __restrict__ Wt1,
                                              __half* __restrict__ Wt2,
                                              int* __restrict__ grel)
{
    int b = blockIdx.x;            // 0..7
    int t = threadIdx.x;
    if (b == 0) {
#pragma unroll
        for (int i = 0; i < 2; ++i) grel[t + 256 * i] = 0;
    }
    const float* W = (b < 4) ? W1 : W2;
    __half* Wt = (b < 4) ? Wt1 : Wt2;
    int q = b & 3;
#pragma unroll
    for (int i = 0; i < 4; ++i) {
        int idx = q * 1024 + t + 256 * i;   // float4 index 0..4095
        int k = idx >> 5, nq = idx & 31;
        float4 v = ((const float4*)W)[idx];
        const float* vp = (const float*)&v;
#pragma unroll
        for (int j = 0; j < 4; ++j)
            Wt[(size_t)(nq * 4 + j) * 128 + k] = __float2half(vp[j]);
    }
}

// ------- MFMA GEMM + fused attention coefficients (device body) -------
template<typename AT>
__device__ __forceinline__ void gemm_body(char* lds,
                                          const AT* __restrict__ A,
                                          const __half* __restrict__ Wt,
                                          const float* __restrict__ al,
                                          const float* __restrict__ ar,
                                          __half* __restrict__ feat_h,
                                          float* __restrict__ el,
                                          float* __restrict__ er,
                                          int nrows, int bid)
{
    int t = threadIdx.x;
    int r0 = bid * 64;

    // ---- stage A (64 rows x 128 k, fp16, swizzled) ----
#pragma unroll
    for (int i = 0; i < 4; ++i) {
        int cid = t + 256 * i;            // 0..1023 : 16B chunks
        int row = cid >> 4, kc = cid & 15;
        int gr = r0 + row;
        f16x8 hv;
        if constexpr (std::is_same<AT, float>::value) {
            float4 v0 = make_float4(0, 0, 0, 0), v1 = v0;
            if (gr < nrows) {
                v0 = ((const float4*)A)[(size_t)gr * 32 + kc * 2];
                v1 = ((const float4*)A)[(size_t)gr * 32 + kc * 2 + 1];
            }
            hv[0] = (_Float16)v0.x; hv[1] = (_Float16)v0.y;
            hv[2] = (_Float16)v0.z; hv[3] = (_Float16)v0.w;
            hv[4] = (_Float16)v1.x; hv[5] = (_Float16)v1.y;
            hv[6] = (_Float16)v1.z; hv[7] = (_Float16)v1.w;
        } else {
            uint4 u = make_uint4(0, 0, 0, 0);
            if (gr < nrows) u = ((const uint4*)A)[(size_t)gr * 16 + kc];
            hv = *(const f16x8*)&u;
        }
        *(f16x8*)(lds + swz(row, kc * 16)) = hv;
    }
    // ---- stage B = Wt (128 n x 128 k, fp16, swizzled) ----
#pragma unroll
    for (int i = 0; i < 8; ++i) {
        int cid = t + 256 * i;            // 0..2047
        int n = cid >> 4, kc = cid & 15;
        uint4 u = ((const uint4*)Wt)[(size_t)n * 16 + kc];
        *(uint4*)(lds + 16384 + swz(n, kc * 16)) = u;
    }
    __syncthreads();

    int w = t >> 6, lane = t & 63;
    int l15 = lane & 15, g = lane >> 4;

    f32x4 acc[8];
#pragma unroll
    for (int ct = 0; ct < 8; ++ct) acc[ct] = (f32x4){0.f, 0.f, 0.f, 0.f};

#pragma unroll
    for (int ks = 0; ks < 4; ++ks) {
        f16x8 a = *(const f16x8*)(lds + swz(w * 16 + l15, ks * 64 + g * 16));
#pragma unroll
        for (int ct = 0; ct < 8; ++ct) {
            f16x8 b = *(const f16x8*)(lds + 16384 + swz(ct * 16 + l15, ks * 64 + g * 16));
            acc[ct] = __builtin_amdgcn_mfma_f32_16x16x32_f16(a, b, acc[ct], 0, 0, 0);
        }
    }

    // ---- feat fp16 store: lane holds C[m][n], m=w*16+g*4+j, n=ct*16+l15 ----
#pragma unroll
    for (int j = 0; j < 4; ++j) {
        int gr = r0 + w * 16 + g * 4 + j;
        if (gr < nrows) {
#pragma unroll
            for (int ct = 0; ct < 8; ++ct)
                feat_h[(size_t)gr * 128 + ct * 16 + l15] = __float2half(acc[ct][j]);
        }
    }

    // ---- fused el/er ----
    float alf[8], arf[8];
#pragma unroll
    for (int z = 0; z < 8; ++z) { alf[z] = al[z * 16 + l15]; arf[z] = ar[z * 16 + l15]; }
    float elv[4][4], erv[4][4];
#pragma unroll
    for (int j = 0; j < 4; ++j)
#pragma unroll
        for (int h = 0; h < 4; ++h) {
            elv[j][h] = acc[2*h][j] * alf[2*h] + acc[2*h+1][j] * alf[2*h+1];
            erv[j][h] = acc[2*h][j] * arf[2*h] + acc[2*h+1][j] * arf[2*h+1];
        }
#pragma unroll
    for (int off = 1; off < 16; off <<= 1) {
#pragma unroll
        for (int j = 0; j < 4; ++j)
#pragma unroll
            for (int h = 0; h < 4; ++h) {
                elv[j][h] += __shfl_xor(elv[j][h], off);
                erv[j][h] += __shfl_xor(erv[j][h], off);
            }
    }
    if (l15 == 0) {
#pragma unroll
        for (int j = 0; j < 4; ++j) {
            int gr = r0 + w * 16 + g * 4 + j;
            if (gr < nrows) {
#pragma unroll
                for (int h = 0; h < 4; ++h) {
                    el[gr * 4 + h] = elv[j][h];
                    er[gr * 4 + h] = erv[j][h];
                }
            }
        }
    }
}

// ---- part A body: partition (dst,src) pairs into per-bucket slabs ----
__device__ __forceinline__ void part_a_body(char* smem,
                                            const int* __restrict__ src,
                                            const int* __restrict__ dst,
                                            int* __restrict__ grel,
                                            unsigned long long* __restrict__ ebuf,
                                            int ne, int nchunk, int bid)
{
    int* cnt   = (int*)smem;            // [512]
    int* rbase = cnt + NBKMAX;          // [512] relative slab start
    int t = threadIdx.x;
    int c0 = bid * nchunk;
    int c1 = c0 + nchunk; if (c1 > ne) c1 = ne;
    for (int b = t; b < NBKMAX; b += 256) cnt[b] = 0;
    __syncthreads();
    for (int i = c0 + t; i < c1; i += 256)
        atomicAdd(&cnt[dst[i] >> BSHIFT], 1);
    __syncthreads();
    for (int b = t; b < NBKMAX; b += 256) {
        int c = cnt[b];
        rbase[b] = c ? atomicAdd(&grel[b], c) : 0;
        cnt[b] = 0;
    }
    __syncthreads();
    for (int i = c0 + t; i < c1; i += 256) {
        int d = dst[i];
        int b = d >> BSHIFT;
        int p = atomicAdd(&cnt[b], 1);
        int slot = rbase[b] + p;
        if (slot < BCAP)
            ebuf[(size_t)b * BCAP + slot] =
                ((unsigned long long)(unsigned)d << 32) | (unsigned)src[i];
    }
}

// ---- merged dispatch: gemm layer-1 blocks + part_a blocks (independent) ----
__global__ __launch_bounds__(256) void gemm1_parta(const float* __restrict__ X,
                                                   const __half* __restrict__ Wt1,
                                                   const float* __restrict__ al,
                                                   const float* __restrict__ ar,
                                                   __half* __restrict__ feat_h,
                                                   float* __restrict__ el,
                                                   float* __restrict__ er, int nrows,
                                                   const int* __restrict__ src,
                                                   const int* __restrict__ dst,
                                                   int* __restrict__ grel,
                                                   unsigned long long* __restrict__ ebuf,
                                                   int ne, int nchunk, int ngemm)
{
    __shared__ __align__(16) char smem[49152];
    int bid = blockIdx.x;
    if (bid < ngemm)
        gemm_body<float>(smem, X, Wt1, al, ar, feat_h, el, er, nrows, bid);
    else
        part_a_body(smem, src, dst, grel, ebuf, ne, nchunk, bid - ngemm);
}

// ---- standalone gemm (layer 2) ----
__global__ __launch_bounds__(256) void gemm_mfma_h(const __half* __restrict__ A,
                                                   const __half* __restrict__ Wt,
                                                   const float* __restrict__ al,
                                                   const float* __restrict__ ar,
                                                   __half* __restrict__ feat_h,
                                                   float* __restrict__ el,
                                                   float* __restrict__ er, int nrows)
{
    __shared__ __align__(16) char smem[49152];
    gemm_body<__half>(smem, A, Wt, al, ar, feat_h, el, er, nrows, blockIdx.x);
}

// pass B: one block per bucket — CSR bases from in-block rescan of grel,
// local node histogram+scan -> offs, then scatter src into final CSR slots.
__global__ __launch_bounds__(256) void part_b(const unsigned long long* __restrict__ ebuf,
                                              const int* __restrict__ grel,
                                              int* __restrict__ offs,
                                              int* __restrict__ ssrc,
                                              int nnodes, int ne)
{
    __shared__ int sc[NBKMAX];
    __shared__ int ws[4];
    __shared__ int hcnt[128];
    __shared__ int curs[128];
    __shared__ int w0tot;
    int b = blockIdx.x;
    int t = threadIdx.x;
    int lane = t & 63;
    scan512_excl(grel, sc, ws, t);
    int node0 = b << BSHIFT;
    int csrbase = sc[b];
    int count = grel[b]; if (count > BCAP) count = BCAP;
    const unsigned long long* eb = ebuf + (size_t)b * BCAP;
    if (t < 128) hcnt[t] = 0;
    __syncthreads();
    for (int i = t; i < count; i += 256) {
        int d = (int)(eb[i] >> 32);
        atomicAdd(&hcnt[d - node0], 1);
    }
    __syncthreads();
    int v = (t < 128) ? hcnt[t] : 0;
    int x = v;
#pragma unroll
    for (int off = 1; off < 64; off <<= 1) {
        int y = __shfl_up(x, off);
        if (lane >= off) x += y;
    }
    if (t == 63) w0tot = x;
    __syncthreads();
    if (t < 128) {
        int incl = x + ((t >= 64) ? w0tot : 0);
        int gpos = csrbase + incl - v;
        curs[t] = gpos;
        int node = node0 + t;
        if (node < nnodes) offs[node] = gpos;
    }
    if (b == 0 && t == 0) offs[nnodes] = ne;
    __syncthreads();
    for (int i = t; i < count; i += 256) {
        unsigned long long e = eb[i];
        int d = (int)(e >> 32);
        int p = atomicAdd(&curs[d - node0], 1);
        ssrc[p] = (int)(unsigned)(e & 0xffffffffu);
    }
}

// ---------------- per-destination softmax + aggregation, 1 wave per node ----------------
// LAYER 1: hbuf_h[n,128] (fp16) = elu(sum_e a*feat[src] + b)
// LAYER 2: out[n,32] (fp32)     = mean_h(sum_e a*feat[src] + b)
template<int LAYER>
__global__ __launch_bounds__(256) void aggregate(const __half2* __restrict__ feat,
                                                 const float* __restrict__ el,
                                                 const float* __restrict__ er,
                                                 const int* __restrict__ offs,
                                                 const int* __restrict__ ssrc,
                                                 const float* __restrict__ bias,
                                                 void* __restrict__ out, int nnodes)
{
    __shared__ float w_sh[4][256];
    int wid  = threadIdx.x >> 6;
    int lane = threadIdx.x & 63;
    int gw = blockIdx.x * 4 + wid;
    if (gw >= nnodes) return;
    int beg = offs[gw], end = offs[gw + 1];
    float4 er4 = ((const float4*)er)[gw];
    const float4* el4 = (const float4*)el;
    int h = lane >> 4;

    float accx = 0.f, accy = 0.f;
    float d0 = 0.f, d1 = 0.f, d2 = 0.f, d3 = 0.f;

    for (int cbeg = beg; cbeg < end; cbeg += 64) {
        int cnt = end - cbeg; if (cnt > 64) cnt = 64;
        int myS = (lane < cnt) ? ssrc[cbeg + lane] : 0;
        float4 e4 = el4[myS];
        float ex0 = 0.f, ex1 = 0.f, ex2 = 0.f, ex3 = 0.f;
        if (lane < cnt) {
            float e;
            e = e4.x + er4.x; ex0 = __expf(fmaxf(e, 0.f) + NEG_SLOPE * fminf(e, 0.f));
            e = e4.y + er4.y; ex1 = __expf(fmaxf(e, 0.f) + NEG_SLOPE * fminf(e, 0.f));
            e = e4.z + er4.z; ex2 = __expf(fmaxf(e, 0.f) + NEG_SLOPE * fminf(e, 0.f));
            e = e4.w + er4.w; ex3 = __expf(fmaxf(e, 0.f) + NEG_SLOPE * fminf(e, 0.f));
            d0 += ex0; d1 += ex1; d2 += ex2; d3 += ex3;
        }
        ((float4*)&w_sh[wid][0])[lane] = make_float4(ex0, ex1, ex2, ex3);
        // wave-private LDS: producer == consumer wave, in-order DS pipe

#pragma unroll
        for (int g = 0; g < 4; ++g) {
            if (g * 16 < cnt) {
                __half2 f[16]; float w[16];
#pragma unroll
                for (int k = 0; k < 16; ++k) {
                    int s = __builtin_amdgcn_readlane(myS, g * 16 + k);
                    f[k] = feat[(size_t)s * 64 + lane];
                    w[k] = w_sh[wid][(g * 16 + k) * 4 + h];
                }
#pragma unroll
                for (int k = 0; k < 16; ++k) {
                    float2 ff = __half22float2(f[k]);
                    accx += ff.x * w[k];
                    accy += ff.y * w[k];
                }
            }
        }
    }

#pragma unroll
    for (int off = 32; off; off >>= 1) {
        d0 += __shfl_xor(d0, off);
        d1 += __shfl_xor(d1, off);
        d2 += __shfl_xor(d2, off);
        d3 += __shfl_xor(d3, off);
    }
    float dh   = h == 0 ? d0 : h == 1 ? d1 : h == 2 ? d2 : d3;
    float invh = dh > 0.f ? 1.f / dh : 0.f;
    accx *= invh; accy *= invh;

    int c = lane * 2;
    if (LAYER == 1) {
        float v0 = accx + bias[c];
        float v1 = accy + bias[c + 1];
        v0 = v0 > 0.f ? v0 : expm1f(v0);
        v1 = v1 > 0.f ? v1 : expm1f(v1);
        ((__half2*)out)[(size_t)gw * 64 + lane] = __floats2half2_rn(v0, v1);
    } else {
        float v0 = accx + bias[c];
        float v1 = accy + bias[c + 1];
        v0 += __shfl_xor(v0, 16); v0 += __shfl_xor(v0, 32);
        v1 += __shfl_xor(v1, 16); v1 += __shfl_xor(v1, 32);
        if (lane < 16)
            ((float2*)out)[(size_t)gw * 16 + lane] = make_float2(v0 * 0.25f, v1 * 0.25f);
    }
}

template __global__ void aggregate<1>(const __half2*, const float*, const float*,
                                      const int*, const int*, const float*, void*, int);
template __global__ void aggregate<2>(const __half2*, const float*, const float*,
                                      const int*, const int*, const float*, void*, int);

// ---------------- launcher ----------------
extern "C" void kernel_launch(void* const* d_in, const int* in_sizes, int n_in,
                              void* d_out, int out_size, void* d_ws, size_t ws_size,
                              hipStream_t stream)
{
    const float* X   = (const float*)d_in[0];
    const int*   src = (const int*)d_in[1];
    const int*   dst = (const int*)d_in[2];
    const float* W1  = (const float*)d_in[3];
    const float* al1 = (const float*)d_in[4];
    const float* ar1 = (const float*)d_in[5];
    const float* b1  = (const float*)d_in[6];
    const float* W2  = (const float*)d_in[7];
    const float* al2 = (const float*)d_in[8];
    const float* ar2 = (const float*)d_in[9];
    const float* b2  = (const float*)d_in[10];
    float* out = (float*)d_out;

    const int N = in_sizes[0] / 128;
    const int E = in_sizes[1];
    const int NBK = (N + 127) >> BSHIFT;
    const int NCH = (E + 255) / 256;           // part_a chunk per block (256 blocks)
    const int NGEMM = (N + 63) / 64;

    size_t off = 0;
    char* base = (char*)d_ws;
    auto alloc = [&](size_t bytes) -> void* {
        void* p = base + off;
        off += (bytes + 255) & ~(size_t)255;
        return p;
    };
    __half* feat_h = (__half*)alloc((size_t)N * 128 * 2);
    __half* hbuf_h = (__half*)alloc((size_t)N * 128 * 2);
    float*  el     = (float*)alloc((size_t)N * 4 * 4);
    float*  er     = (float*)alloc((size_t)N * 4 * 4);
    int*    offs   = (int*)alloc((size_t)(N + 1) * 4);
    int*    ssrc   = (int*)alloc((size_t)E * 4);
    unsigned long long* ebuf = (unsigned long long*)alloc((size_t)NBKMAX * BCAP * 8);
    int*    grel   = (int*)alloc(NBKMAX * 4);
    __half* Wt1    = (__half*)alloc(128 * 128 * 2);
    __half* Wt2    = (__half*)alloc(128 * 128 * 2);
    (void)ws_size; (void)n_in; (void)out_size;

    // d1: weight transposes + grel zeroing
    transp<<<8, 256, 0, stream>>>(W1, W2, Wt1, Wt2, grel);

    // d2: layer-1 MFMA GEMM (+el/er)  ∥  edge partition into bucket slabs
    gemm1_parta<<<NGEMM + 256, 256, 0, stream>>>(X, Wt1, al1, ar1, feat_h, el, er, N,
                                                 src, dst, grel, ebuf, E, NCH, NGEMM);

    // d3: CSR finalize (offs + ssrc)
    part_b<<<NBK, 256, 0, stream>>>(ebuf, grel, offs, ssrc, N, E);

    // d4: layer-1 aggregation -> elu(acc + b1) as fp16 hbuf
    aggregate<1><<<(N + 3) / 4, 256, 0, stream>>>((const __half2*)feat_h, el, er, offs, ssrc, b1, hbuf_h, N);

    // d5: layer-2 GEMM
    gemm_mfma_h<<<NGEMM, 256, 0, stream>>>(hbuf_h, Wt2, al2, ar2, feat_h, el, er, N);

    // d6: layer-2 aggregation -> out
    aggregate<2><<<(N + 3) / 4, 256, 0, stream>>>((const __half2*)feat_h, el, er, offs, ssrc, b2, out, N);
}